// Round 10
// baseline (702.512 us; speedup 1.0000x reference)
//
#include <hip/hip_runtime.h>
#include <math.h>

#define NN 50000
#define NE 800000
#define HEADS 4
#define HID 64
#define HD 256          // HEADS*HID flattened feature dim
#define NEG_SLOPE 0.2f
#define NCHUNK 49       // ceil(50000/1024)

typedef __attribute__((ext_vector_type(8))) short short8;
typedef __attribute__((ext_vector_type(4))) float f32x4;

__device__ __forceinline__ unsigned short f2bf(float f) {
    unsigned u = __float_as_uint(f);
    u += 0x7fff + ((u >> 16) & 1);          // RNE
    return (unsigned short)(u >> 16);
}
__device__ __forceinline__ float bf2f(unsigned short b) {
    return __uint_as_float(((unsigned)b) << 16);
}

// ---------------- CSR build ----------------
__global__ void count_kernel(const int* __restrict__ dst, int* __restrict__ cnt) {
    int e = (blockIdx.x * 256 + threadIdx.x) * 2;
    if (e + 1 < NE) {
        int2 d = *(const int2*)&dst[e];
        atomicAdd(&cnt[d.x], 1);
        atomicAdd(&cnt[d.y], 1);
    } else if (e < NE) {
        atomicAdd(&cnt[dst[e]], 1);
    }
}

__global__ void chunk_sum_kernel(const int* __restrict__ cnt, int* __restrict__ csum, int n) {
    __shared__ int sdata[256];
    int base = blockIdx.x * 1024;
    int t = threadIdx.x;
    int s = 0;
    for (int i = t; i < 1024; i += 256) {
        int idx = base + i;
        if (idx < n) s += cnt[idx];
    }
    sdata[t] = s; __syncthreads();
    for (int off = 128; off > 0; off >>= 1) {
        if (t < off) sdata[t] += sdata[t + off];
        __syncthreads();
    }
    if (t == 0) csum[blockIdx.x] = sdata[0];
}

// rowptr + cursor-init; chunk offset computed in-block from csum (no separate scan pass)
__global__ void rowptr_kernel(const int* __restrict__ cnt, const int* __restrict__ csum,
                              int* __restrict__ rowptr, int* __restrict__ cursor, int n) {
    __shared__ int buf[1024];
    __shared__ int chunkOff;
    int t = threadIdx.x;
    int idx = blockIdx.x * 1024 + t;
    if (t < 64) {
        int partial = 0;
        for (int i = t; i < blockIdx.x; i += 64) partial += csum[i];
#pragma unroll
        for (int off = 32; off > 0; off >>= 1) partial += __shfl_down(partial, off);
        if (t == 0) chunkOff = partial;
    }
    int v = (idx < n) ? cnt[idx] : 0;
    buf[t] = v; __syncthreads();
    for (int off = 1; off < 1024; off <<= 1) {
        int tmp = (t >= off) ? buf[t - off] : 0;
        __syncthreads();
        buf[t] += tmp;
        __syncthreads();
    }
    int excl = buf[t] - v + chunkOff;
    if (idx < n) { rowptr[idx] = excl; cursor[idx] = excl; }
    if (idx == n - 1) rowptr[n] = excl + v;
}

__global__ void scatter_kernel(const int* __restrict__ src, const int* __restrict__ dst,
                               int* __restrict__ cursor, int* __restrict__ csr_src) {
    int e = (blockIdx.x * 256 + threadIdx.x) * 2;
    if (e + 1 < NE) {
        int2 d = *(const int2*)&dst[e];
        int2 s = *(const int2*)&src[e];
        int p0 = atomicAdd(&cursor[d.x], 1);
        csr_src[p0] = s.x;
        int p1 = atomicAdd(&cursor[d.y], 1);
        csr_src[p1] = s.y;
    } else if (e < NE) {
        int p = atomicAdd(&cursor[dst[e]], 1);
        csr_src[p] = src[e];
    }
}

// ---------------- prep: W fragment split (3 layers) + X hi/lo split, one dispatch ----------------
// Wf layout: ((kb*16 + tile)*64 + lane)*16 + {j: hi, 8+j: lo}
__device__ __forceinline__ void wsplit_one(const float* W, unsigned short* Wf, int idx) {
    int lane = idx & 63;
    int tile = (idx >> 6) & 15;
    int kb   = idx >> 10;
    int col  = tile * 16 + (lane & 15);
    int krow = kb * 32 + (lane >> 4) * 8;
    unsigned short* p = Wf + (size_t)idx * 16;
#pragma unroll
    for (int j = 0; j < 8; j++) {
        float v = W[(size_t)(krow + j) * HD + col];
        unsigned short h = f2bf(v);
        unsigned short l = f2bf(v - bf2f(h));
        p[j] = h;
        p[8 + j] = l;
    }
}

#define XSPLIT4 (NN * 128 / 4)     // 1,600,000 float4s

// Xhl layout (K=128): per row, 16 k-octs; each oct = 16 ushorts {8 hi | 8 lo} (32 B)
__global__ void prep_kernel(const float* __restrict__ X, ushort* __restrict__ Xhl,
                            const float* __restrict__ W0, unsigned short* __restrict__ Wf0,
                            const float* __restrict__ W1, unsigned short* __restrict__ Wf1,
                            const float* __restrict__ W2, unsigned short* __restrict__ Wf2) {
    int idx = blockIdx.x * 256 + threadIdx.x;
    if (idx < XSPLIT4) {
        float4 v = ((const float4*)X)[idx];
        ushort4 h, l;
        h.x = f2bf(v.x); l.x = f2bf(v.x - bf2f(h.x));
        h.y = f2bf(v.y); l.y = f2bf(v.y - bf2f(h.y));
        h.z = f2bf(v.z); l.z = f2bf(v.z - bf2f(h.z));
        h.w = f2bf(v.w); l.w = f2bf(v.w - bf2f(h.w));
        int e = idx * 4;
        int row = e >> 7;              // K=128
        int kk = e & 127;
        int base = (row * 16 + (kk >> 3)) * 16 + (kk & 7);
        *(ushort4*)&Xhl[base] = h;
        *(ushort4*)&Xhl[base + 8] = l;
    }
    const int n0 = 4 * 16 * 64;            // K=128
    const int n1 = 8 * 16 * 64;            // K=256
    if (idx < n0) wsplit_one(W0, Wf0, idx);
    else if (idx < n0 + n1) wsplit_one(W1, Wf1, idx - n0);
    else if (idx < n0 + 2 * n1) wsplit_one(W2, Wf2, idx - n0 - n1);
}

// ---------------- MFMA GEMM + fused el/er ----------------
// H[N,256] = (Xhi+Xlo)[N,K] @ W[K,256], bf16 hi/lo (3 MFMA products, lo*lo dropped).
// Block: 64 rows x 256 cols, 4 waves; wave w owns head w's 64 cols.
// Per wave: 4 row-tiles x 4 col-tiles of 16x16x32. No LDS, no barriers.
// 3 waves/SIMD (VGPR ~150 <= 168): TLP hides the unpipelined K-loop latency.
template <int K>
__global__ __launch_bounds__(256, 3) void mfma_gemm_kernel(
    const ushort* __restrict__ Xhl,
    const unsigned short* __restrict__ Wf,
    float* __restrict__ H,
    const float* __restrict__ al, const float* __restrict__ ar,
    float* __restrict__ el, float* __restrict__ er) {
    constexpr int KO = K / 8;      // octs per row
    int tid = threadIdx.x;
    int w = tid >> 6;              // wave index = head
    int lane = tid & 63;
    int rowBase = blockIdx.x * 64;
    int mrow = lane & 15;          // A: m within tile; C: col within tile
    int q = lane >> 4;             // quad

    f32x4 acc[4][4];
#pragma unroll
    for (int r = 0; r < 4; r++)
#pragma unroll
        for (int c = 0; c < 4; c++) {
            f32x4 z = {0.f, 0.f, 0.f, 0.f};
            acc[r][c] = z;
        }

    for (int k0 = 0; k0 < K; k0 += 32) {
        short8 Ah[4], Al_[4];
#pragma unroll
        for (int r = 0; r < 4; r++) {
            int row = rowBase + r * 16 + mrow;
            row = row < NN ? row : NN - 1;     // clamp; OOB rows never stored
            size_t o = ((size_t)row * KO + (k0 >> 3) + q) * 16;
            Ah[r]  = *(const short8*)&Xhl[o];
            Al_[r] = *(const short8*)&Xhl[o + 8];
        }
        const unsigned short* wfk =
            Wf + (((size_t)(k0 >> 5) * 16 + w * 4) * 64 + lane) * 16;
        short8 Wh[4], Wl_[4];
#pragma unroll
        for (int c = 0; c < 4; c++) {
            Wh[c]  = *(const short8*)(wfk + (size_t)c * 64 * 16);
            Wl_[c] = *(const short8*)(wfk + (size_t)c * 64 * 16 + 8);
        }
#pragma unroll
        for (int c = 0; c < 4; c++)
#pragma unroll
            for (int r = 0; r < 4; r++) {
                acc[r][c] = __builtin_amdgcn_mfma_f32_16x16x32_bf16(Ah[r],  Wh[c],  acc[r][c], 0, 0, 0);
                acc[r][c] = __builtin_amdgcn_mfma_f32_16x16x32_bf16(Ah[r],  Wl_[c], acc[r][c], 0, 0, 0);
                acc[r][c] = __builtin_amdgcn_mfma_f32_16x16x32_bf16(Al_[r], Wh[c],  acc[r][c], 0, 0, 0);
            }
    }

    // --- epilogue: store H + fused el/er (head w) ---
    int n0 = w * 64;
    float alv[4], arv[4];
#pragma unroll
    for (int c = 0; c < 4; c++) {
        alv[c] = al[n0 + c * 16 + mrow];
        arv[c] = ar[n0 + c * 16 + mrow];
    }
#pragma unroll
    for (int r = 0; r < 4; r++) {
        float pl[4] = {0.f, 0.f, 0.f, 0.f};
        float pr[4] = {0.f, 0.f, 0.f, 0.f};
#pragma unroll
        for (int c = 0; c < 4; c++)
#pragma unroll
            for (int g = 0; g < 4; g++) {
                pl[g] += acc[r][c][g] * alv[c];
                pr[g] += acc[r][c][g] * arv[c];
            }
#pragma unroll
        for (int g = 0; g < 4; g++) {
#pragma unroll
            for (int off = 1; off < 16; off <<= 1) {
                pl[g] += __shfl_xor(pl[g], off);
                pr[g] += __shfl_xor(pr[g], off);
            }
        }
#pragma unroll
        for (int g = 0; g < 4; g++) {
            int row = rowBase + r * 16 + q * 4 + g;
            if (row < NN) {
#pragma unroll
                for (int c = 0; c < 4; c++)
                    H[(size_t)row * HD + n0 + c * 16 + mrow] = acc[r][c][g];
                if (mrow == 0) {
                    el[row * 4 + w] = pl[g];
                    er[row * 4 + w] = pr[g];
                }
            }
        }
    }
}

// ---------------- GAT per-node: single-pass flash softmax, unroll-2 ----------------
// Split into node-range halves so every heavy dispatch is visible in top-5 profiles.
__device__ __forceinline__ float lrelu(float x) { return x > 0.f ? x : NEG_SLOPE * x; }

template <int FINAL>
__global__ __launch_bounds__(256) void gat_node_kernel(
    const float* __restrict__ H, const float* __restrict__ el, const float* __restrict__ er,
    const int* __restrict__ rowptr, const int* __restrict__ csr_src,
    ushort* __restrict__ out_hl,
    const float* __restrict__ Wout, const float* __restrict__ bout,
    float* __restrict__ final_out, int vbase) {
    int wave = threadIdx.x >> 6, lane = threadIdx.x & 63;
    int v = vbase + blockIdx.x * 4 + wave;
    if (v >= NN) return;
    int beg = rowptr[v], end = rowptr[v + 1];

    int hh = lane >> 4;                    // head for this lane's feature slice
    float er_h = er[v * 4 + hh];

    float m = -INFINITY;
    float ssum = 0.f;
    float4 acc = make_float4(0.f, 0.f, 0.f, 0.f);

    int idx = beg;
    for (; idx + 2 <= end; idx += 2) {
        int s0 = csr_src[idx];
        int s1 = csr_src[idx + 1];
        float el0 = el[s0 * 4 + hh];
        float el1 = el[s1 * 4 + hh];
        float4 h0 = *(const float4*)&H[(long)s0 * HD + lane * 4];
        float4 h1 = *(const float4*)&H[(long)s1 * HD + lane * 4];
        float e0 = lrelu(el0 + er_h);
        float e1 = lrelu(el1 + er_h);
        float mn = fmaxf(m, fmaxf(e0, e1));
        float sc = __expf(m - mn);
        float w0 = __expf(e0 - mn);
        float w1 = __expf(e1 - mn);
        ssum = ssum * sc + w0 + w1;
        acc.x = acc.x * sc + w0 * h0.x + w1 * h1.x;
        acc.y = acc.y * sc + w0 * h0.y + w1 * h1.y;
        acc.z = acc.z * sc + w0 * h0.z + w1 * h1.z;
        acc.w = acc.w * sc + w0 * h0.w + w1 * h1.w;
        m = mn;
    }
    if (idx < end) {
        int s0 = csr_src[idx];
        float el0 = el[s0 * 4 + hh];
        float4 h0 = *(const float4*)&H[(long)s0 * HD + lane * 4];
        float e0 = lrelu(el0 + er_h);
        float mn = fmaxf(m, e0);
        float sc = __expf(m - mn);
        float w0 = __expf(e0 - mn);
        ssum = ssum * sc + w0;
        acc.x = acc.x * sc + w0 * h0.x;
        acc.y = acc.y * sc + w0 * h0.y;
        acc.z = acc.z * sc + w0 * h0.z;
        acc.w = acc.w * sc + w0 * h0.w;
    }

    float inv = 1.0f / (ssum + 1e-9f);
    acc.x *= inv; acc.y *= inv; acc.z *= inv; acc.w *= inv;

    // elu
    acc.x = acc.x > 0.f ? acc.x : expm1f(acc.x);
    acc.y = acc.y > 0.f ? acc.y : expm1f(acc.y);
    acc.z = acc.z > 0.f ? acc.z : expm1f(acc.z);
    acc.w = acc.w > 0.f ? acc.w : expm1f(acc.w);

    if (!FINAL) {
        // write hi/lo bf16 split, interleaved oct layout {8 hi | 8 lo} (next GEMM's A)
        ushort4 hv, lv;
        hv.x = f2bf(acc.x); lv.x = f2bf(acc.x - bf2f(hv.x));
        hv.y = f2bf(acc.y); lv.y = f2bf(acc.y - bf2f(hv.y));
        hv.z = f2bf(acc.z); lv.z = f2bf(acc.z - bf2f(hv.z));
        hv.w = f2bf(acc.w); lv.w = f2bf(acc.w - bf2f(hv.w));
        size_t base = ((size_t)v * 32 + (lane >> 1)) * 16 + (lane & 1) * 4;   // HD=256 -> 32 octs
        *(ushort4*)&out_hl[base] = hv;
        *(ushort4*)&out_hl[base + 8] = lv;
    } else {
        // mean over heads (lanes l, l^16, l^32 hold same d-range, different head)
        acc.x += __shfl_xor(acc.x, 16); acc.x += __shfl_xor(acc.x, 32);
        acc.y += __shfl_xor(acc.y, 16); acc.y += __shfl_xor(acc.y, 32);
        acc.z += __shfl_xor(acc.z, 16); acc.z += __shfl_xor(acc.z, 32);
        acc.w += __shfl_xor(acc.w, 16); acc.w += __shfl_xor(acc.w, 32);
        float4 w4 = *(const float4*)&Wout[(lane & 15) * 4];
        float p = 0.25f * (acc.x * w4.x + acc.y * w4.y + acc.z * w4.z + acc.w * w4.w);
        p += __shfl_xor(p, 1);
        p += __shfl_xor(p, 2);
        p += __shfl_xor(p, 4);
        p += __shfl_xor(p, 8);
        if (lane == 0) final_out[v] = fmaxf(p + bout[0], 0.f);
    }
}

extern "C" void kernel_launch(void* const* d_in, const int* in_sizes, int n_in,
                              void* d_out, int out_size, void* d_ws, size_t ws_size,
                              hipStream_t stream) {
    const float* x    = (const float*)d_in[0];
    const int*   src  = (const int*)d_in[1];
    const int*   dst  = (const int*)d_in[2];
    const float* W0   = (const float*)d_in[3];
    const float* al0  = (const float*)d_in[4];
    const float* ar0  = (const float*)d_in[5];
    const float* W1   = (const float*)d_in[6];
    const float* al1  = (const float*)d_in[7];
    const float* ar1  = (const float*)d_in[8];
    const float* W2   = (const float*)d_in[9];
    const float* al2  = (const float*)d_in[10];
    const float* ar2  = (const float*)d_in[11];
    const float* Wout = (const float*)d_in[12];
    const float* bout = (const float*)d_in[13];
    float* outp = (float*)d_out;

    char* ws = (char*)d_ws;
    size_t off = 0;
    auto carve = [&](size_t n) -> char* {
        char* p = ws + off;
        off += (n + 255) & ~(size_t)255;
        return p;
    };
    float*  h_buf  = (float*)carve((size_t)NN * HD * 4);
    ushort* xhl    = (ushort*)carve((size_t)NN * HD * 2 * 2);  // interleaved hi|lo octs
    float*  el     = (float*)carve((size_t)NN * HEADS * 4);
    float*  er     = (float*)carve((size_t)NN * HEADS * 4);
    int*    cnt    = (int*)carve((size_t)NN * 4);
    int*    cursor = (int*)carve((size_t)NN * 4);
    int*    rowptr = (int*)carve((size_t)(NN + 1) * 4);
    int*    csr_src= (int*)carve((size_t)NE * 4);
    int*    csum   = (int*)carve(64 * 4);
    unsigned short* Wf0 = (unsigned short*)carve((size_t)4 * 16 * 64 * 16 * 2);   // K=128
    unsigned short* Wf1 = (unsigned short*)carve((size_t)8 * 16 * 64 * 16 * 2);   // K=256
    unsigned short* Wf2 = (unsigned short*)carve((size_t)8 * 16 * 64 * 16 * 2);   // K=256

    // ---- prep: all W splits + layer-0 X split in one dispatch ----
    prep_kernel<<<(XSPLIT4 + 255) / 256, 256, 0, stream>>>(x, xhl, W0, Wf0, W1, Wf1, W2, Wf2);

    // ---- build dst-CSR: memset, count, chunk_sum, rowptr(+cursor), scatter ----
    hipMemsetAsync(cnt, 0, (size_t)NN * 4, stream);
    count_kernel<<<(NE / 2 + 255) / 256, 256, 0, stream>>>(dst, cnt);
    chunk_sum_kernel<<<NCHUNK, 256, 0, stream>>>(cnt, csum, NN);
    rowptr_kernel<<<NCHUNK, 1024, 0, stream>>>(cnt, csum, rowptr, cursor, NN);
    scatter_kernel<<<(NE / 2 + 255) / 256, 256, 0, stream>>>(src, dst, cursor, csr_src);

    int gGemm = (NN + 63) / 64;            // 782
    const int HALF = 25000;
    int gHalf = HALF / 4;                  // 6250 blocks per half

    // ---- layer 0 ----
    mfma_gemm_kernel<128><<<gGemm, 256, 0, stream>>>(xhl, Wf0, h_buf, al0, ar0, el, er);
    gat_node_kernel<0><<<gHalf, 256, 0, stream>>>(h_buf, el, er, rowptr, csr_src,
                                                  xhl, nullptr, nullptr, nullptr, 0);
    gat_node_kernel<0><<<gHalf, 256, 0, stream>>>(h_buf, el, er, rowptr, csr_src,
                                                  xhl, nullptr, nullptr, nullptr, HALF);
    // ---- layer 1 ----
    mfma_gemm_kernel<256><<<gGemm, 256, 0, stream>>>(xhl, Wf1, h_buf, al1, ar1, el, er);
    gat_node_kernel<0><<<gHalf, 256, 0, stream>>>(h_buf, el, er, rowptr, csr_src,
                                                  xhl, nullptr, nullptr, nullptr, 0);
    gat_node_kernel<0><<<gHalf, 256, 0, stream>>>(h_buf, el, er, rowptr, csr_src,
                                                  xhl, nullptr, nullptr, nullptr, HALF);
    // ---- layer 2 (final: fused elu + head-mean + Wout + relu) ----
    mfma_gemm_kernel<256><<<gGemm, 256, 0, stream>>>(xhl, Wf2, h_buf, al2, ar2, el, er);
    gat_node_kernel<1><<<gHalf, 256, 0, stream>>>(h_buf, el, er, rowptr, csr_src,
                                                  nullptr, Wout, bout, outp, 0);
    gat_node_kernel<1><<<gHalf, 256, 0, stream>>>(h_buf, el, er, rowptr, csr_src,
                                                  nullptr, Wout, bout, outp, HALF);
}

// Round 11
// 687.222 us; speedup vs baseline: 1.0222x; 1.0222x over previous
//
#include <hip/hip_runtime.h>
#include <math.h>

#define NN 50000
#define NE 800000
#define HEADS 4
#define HID 64
#define HD 256          // HEADS*HID flattened feature dim
#define NEG_SLOPE 0.2f
#define NCHUNK 49       // ceil(50000/1024)
#define NTILES 3125     // NN/16 row-tiles (exact)

typedef __attribute__((ext_vector_type(8))) short short8;
typedef __attribute__((ext_vector_type(4))) float f32x4;

__device__ __forceinline__ unsigned short f2bf(float f) {
    unsigned u = __float_as_uint(f);
    u += 0x7fff + ((u >> 16) & 1);          // RNE
    return (unsigned short)(u >> 16);
}
__device__ __forceinline__ float bf2f(unsigned short b) {
    return __uint_as_float(((unsigned)b) << 16);
}

// ---------------- CSR build ----------------
__global__ void count_kernel(const int* __restrict__ dst, int* __restrict__ cnt) {
    int e = (blockIdx.x * 256 + threadIdx.x) * 2;
    if (e + 1 < NE) {
        int2 d = *(const int2*)&dst[e];
        atomicAdd(&cnt[d.x], 1);
        atomicAdd(&cnt[d.y], 1);
    } else if (e < NE) {
        atomicAdd(&cnt[dst[e]], 1);
    }
}

__global__ void chunk_sum_kernel(const int* __restrict__ cnt, int* __restrict__ csum, int n) {
    __shared__ int sdata[256];
    int base = blockIdx.x * 1024;
    int t = threadIdx.x;
    int s = 0;
    for (int i = t; i < 1024; i += 256) {
        int idx = base + i;
        if (idx < n) s += cnt[idx];
    }
    sdata[t] = s; __syncthreads();
    for (int off = 128; off > 0; off >>= 1) {
        if (t < off) sdata[t] += sdata[t + off];
        __syncthreads();
    }
    if (t == 0) csum[blockIdx.x] = sdata[0];
}

// rowptr + cursor-init; chunk offset computed in-block from csum (no separate scan pass)
__global__ void rowptr_kernel(const int* __restrict__ cnt, const int* __restrict__ csum,
                              int* __restrict__ rowptr, int* __restrict__ cursor, int n) {
    __shared__ int buf[1024];
    __shared__ int chunkOff;
    int t = threadIdx.x;
    int idx = blockIdx.x * 1024 + t;
    if (t < 64) {
        int partial = 0;
        for (int i = t; i < blockIdx.x; i += 64) partial += csum[i];
#pragma unroll
        for (int off = 32; off > 0; off >>= 1) partial += __shfl_down(partial, off);
        if (t == 0) chunkOff = partial;
    }
    int v = (idx < n) ? cnt[idx] : 0;
    buf[t] = v; __syncthreads();
    for (int off = 1; off < 1024; off <<= 1) {
        int tmp = (t >= off) ? buf[t - off] : 0;
        __syncthreads();
        buf[t] += tmp;
        __syncthreads();
    }
    int excl = buf[t] - v + chunkOff;
    if (idx < n) { rowptr[idx] = excl; cursor[idx] = excl; }
    if (idx == n - 1) rowptr[n] = excl + v;
}

__global__ void scatter_kernel(const int* __restrict__ src, const int* __restrict__ dst,
                               int* __restrict__ cursor, int* __restrict__ csr_src) {
    int e = (blockIdx.x * 256 + threadIdx.x) * 2;
    if (e + 1 < NE) {
        int2 d = *(const int2*)&dst[e];
        int2 s = *(const int2*)&src[e];
        int p0 = atomicAdd(&cursor[d.x], 1);
        csr_src[p0] = s.x;
        int p1 = atomicAdd(&cursor[d.y], 1);
        csr_src[p1] = s.y;
    } else if (e < NE) {
        int p = atomicAdd(&cursor[dst[e]], 1);
        csr_src[p] = src[e];
    }
}

// ---------------- fragment-major layouts ----------------
// Xf (A operand): block (t, kb) = 16 rows x 32 k. hi half then lo half:
//   Xf[(((t*KB + kb)*2 + h)*64 + flane)*8 + j],  flane = q*16 + mrow,
//   value = split(X[t*16 + mrow][kb*32 + q*8 + j]),  h=0 hi, h=1 lo.
// Wf (B operand): block (kb, tile) = 32 k x 16 cols, same hi/lo split-region:
//   Wf[(((kb*16 + tile)*2 + h)*64 + lane)*8 + j]
//   value = split(W[kb*32 + (lane>>4)*8 + j][tile*16 + (lane&15)]).
// Every GEMM load: lane-contiguous 16 B -> 1 KB/instruction, fully coalesced.

__device__ __forceinline__ void wsplit_one(const float* W, unsigned short* Wf, int idx) {
    int lane = idx & 63;
    int tile = (idx >> 6) & 15;
    int kb   = idx >> 10;
    int col  = tile * 16 + (lane & 15);
    int krow = kb * 32 + (lane >> 4) * 8;
    unsigned short* p = Wf + ((size_t)(kb * 16 + tile) * 2 * 64 + lane) * 8;
#pragma unroll
    for (int j = 0; j < 8; j++) {
        float v = W[(size_t)(krow + j) * HD + col];
        unsigned short h = f2bf(v);
        unsigned short l = f2bf(v - bf2f(h));
        p[j] = h;
        p[512 + j] = l;            // lo region: +64*8
    }
}

#define XSPLIT4 (NN * 128 / 4)     // 1,600,000 float4s

__global__ void prep_kernel(const float* __restrict__ X, ushort* __restrict__ Xf,
                            const float* __restrict__ W0, unsigned short* __restrict__ Wf0,
                            const float* __restrict__ W1, unsigned short* __restrict__ Wf1,
                            const float* __restrict__ W2, unsigned short* __restrict__ Wf2) {
    int idx = blockIdx.x * 256 + threadIdx.x;
    if (idx < XSPLIT4) {
        float4 v = ((const float4*)X)[idx];
        ushort4 h, l;
        h.x = f2bf(v.x); l.x = f2bf(v.x - bf2f(h.x));
        h.y = f2bf(v.y); l.y = f2bf(v.y - bf2f(h.y));
        h.z = f2bf(v.z); l.z = f2bf(v.z - bf2f(h.z));
        h.w = f2bf(v.w); l.w = f2bf(v.w - bf2f(h.w));
        int e = idx * 4;               // flat element, K=128
        int row = e >> 7;
        int kk = e & 127;
        int t = row >> 4, mrow = row & 15;
        int oct = kk >> 3;
        int kb = oct >> 2, q = oct & 3;
        int hj = kk & 7;               // 0 or 4
        size_t base = (((size_t)(t * 4 + kb) * 2) * 64 + q * 16 + mrow) * 8 + hj;
        *(ushort4*)&Xf[base] = h;
        *(ushort4*)&Xf[base + 512] = l;
    }
    const int n0 = 4 * 16 * 64;            // K=128
    const int n1 = 8 * 16 * 64;            // K=256
    if (idx < n0) wsplit_one(W0, Wf0, idx);
    else if (idx < n0 + n1) wsplit_one(W1, Wf1, idx - n0);
    else if (idx < n0 + 2 * n1) wsplit_one(W2, Wf2, idx - n0 - n1);
}

// ---------------- MFMA GEMM + fused el/er ----------------
// H[N,256] = (Xhi+Xlo)[N,K] @ W[K,256], bf16 hi/lo (3 MFMA products, lo*lo dropped).
// Block: 64 rows x 256 cols, 4 waves; wave w owns head w's 64 cols.
// All A/W loads fully coalesced via fragment-major layout. No LDS, no barriers.
template <int K>
__global__ __launch_bounds__(256, 3) void mfma_gemm_kernel(
    const ushort* __restrict__ Xf,
    const unsigned short* __restrict__ Wf,
    float* __restrict__ H,
    const float* __restrict__ al, const float* __restrict__ ar,
    float* __restrict__ el, float* __restrict__ er) {
    constexpr int KB = K / 32;     // k-blocks
    int tid = threadIdx.x;
    int w = tid >> 6;              // wave index = head
    int lane = tid & 63;
    int rowBase = blockIdx.x * 64;
    int mrow = lane & 15;          // C: col within tile
    int q = lane >> 4;             // quad

    int trow[4];
#pragma unroll
    for (int r = 0; r < 4; r++) {
        int t = blockIdx.x * 4 + r;
        trow[r] = t < NTILES ? t : NTILES - 1;   // clamp; OOB tiles never stored
    }

    f32x4 acc[4][4];
#pragma unroll
    for (int r = 0; r < 4; r++)
#pragma unroll
        for (int c = 0; c < 4; c++) {
            f32x4 z = {0.f, 0.f, 0.f, 0.f};
            acc[r][c] = z;
        }

    for (int kb = 0; kb < KB; kb++) {
        short8 Ah[4], Al_[4];
#pragma unroll
        for (int r = 0; r < 4; r++) {
            const ushort* ap = Xf + (((size_t)(trow[r] * KB + kb) * 2) * 64 + lane) * 8;
            Ah[r]  = *(const short8*)ap;
            Al_[r] = *(const short8*)(ap + 512);
        }
        short8 Wh[4], Wl_[4];
#pragma unroll
        for (int c = 0; c < 4; c++) {
            const unsigned short* wp =
                Wf + (((size_t)(kb * 16 + w * 4 + c) * 2) * 64 + lane) * 8;
            Wh[c]  = *(const short8*)wp;
            Wl_[c] = *(const short8*)(wp + 512);
        }
#pragma unroll
        for (int c = 0; c < 4; c++)
#pragma unroll
            for (int r = 0; r < 4; r++) {
                acc[r][c] = __builtin_amdgcn_mfma_f32_16x16x32_bf16(Ah[r],  Wh[c],  acc[r][c], 0, 0, 0);
                acc[r][c] = __builtin_amdgcn_mfma_f32_16x16x32_bf16(Ah[r],  Wl_[c], acc[r][c], 0, 0, 0);
                acc[r][c] = __builtin_amdgcn_mfma_f32_16x16x32_bf16(Al_[r], Wh[c],  acc[r][c], 0, 0, 0);
            }
    }

    // --- epilogue: store H + fused el/er (head w) ---
    int n0 = w * 64;
    float alv[4], arv[4];
#pragma unroll
    for (int c = 0; c < 4; c++) {
        alv[c] = al[n0 + c * 16 + mrow];
        arv[c] = ar[n0 + c * 16 + mrow];
    }
#pragma unroll
    for (int r = 0; r < 4; r++) {
        float pl[4] = {0.f, 0.f, 0.f, 0.f};
        float pr[4] = {0.f, 0.f, 0.f, 0.f};
#pragma unroll
        for (int c = 0; c < 4; c++)
#pragma unroll
            for (int g = 0; g < 4; g++) {
                pl[g] += acc[r][c][g] * alv[c];
                pr[g] += acc[r][c][g] * arv[c];
            }
#pragma unroll
        for (int g = 0; g < 4; g++) {
#pragma unroll
            for (int off = 1; off < 16; off <<= 1) {
                pl[g] += __shfl_xor(pl[g], off);
                pr[g] += __shfl_xor(pr[g], off);
            }
        }
#pragma unroll
        for (int g = 0; g < 4; g++) {
            int row = rowBase + r * 16 + q * 4 + g;
            if (row < NN) {
#pragma unroll
                for (int c = 0; c < 4; c++)
                    H[(size_t)row * HD + n0 + c * 16 + mrow] = acc[r][c][g];
                if (mrow == 0) {
                    el[row * 4 + w] = pl[g];
                    er[row * 4 + w] = pr[g];
                }
            }
        }
    }
}

// ---------------- GAT per-node: single-pass flash softmax, unroll-2 ----------------
__device__ __forceinline__ float lrelu(float x) { return x > 0.f ? x : NEG_SLOPE * x; }

template <int FINAL>
__global__ __launch_bounds__(256) void gat_node_kernel(
    const float* __restrict__ H, const float* __restrict__ el, const float* __restrict__ er,
    const int* __restrict__ rowptr, const int* __restrict__ csr_src,
    ushort* __restrict__ out_f,
    const float* __restrict__ Wout, const float* __restrict__ bout,
    float* __restrict__ final_out) {
    int wave = threadIdx.x >> 6, lane = threadIdx.x & 63;
    int v = blockIdx.x * 4 + wave;
    if (v >= NN) return;
    int beg = rowptr[v], end = rowptr[v + 1];

    int hh = lane >> 4;                    // head for this lane's feature slice
    float er_h = er[v * 4 + hh];

    float m = -INFINITY;
    float ssum = 0.f;
    float4 acc = make_float4(0.f, 0.f, 0.f, 0.f);

    int idx = beg;
    for (; idx + 2 <= end; idx += 2) {
        int s0 = csr_src[idx];
        int s1 = csr_src[idx + 1];
        float el0 = el[s0 * 4 + hh];
        float el1 = el[s1 * 4 + hh];
        float4 h0 = *(const float4*)&H[(long)s0 * HD + lane * 4];
        float4 h1 = *(const float4*)&H[(long)s1 * HD + lane * 4];
        float e0 = lrelu(el0 + er_h);
        float e1 = lrelu(el1 + er_h);
        float mn = fmaxf(m, fmaxf(e0, e1));
        float sc = __expf(m - mn);
        float w0 = __expf(e0 - mn);
        float w1 = __expf(e1 - mn);
        ssum = ssum * sc + w0 + w1;
        acc.x = acc.x * sc + w0 * h0.x + w1 * h1.x;
        acc.y = acc.y * sc + w0 * h0.y + w1 * h1.y;
        acc.z = acc.z * sc + w0 * h0.z + w1 * h1.z;
        acc.w = acc.w * sc + w0 * h0.w + w1 * h1.w;
        m = mn;
    }
    if (idx < end) {
        int s0 = csr_src[idx];
        float el0 = el[s0 * 4 + hh];
        float4 h0 = *(const float4*)&H[(long)s0 * HD + lane * 4];
        float e0 = lrelu(el0 + er_h);
        float mn = fmaxf(m, e0);
        float sc = __expf(m - mn);
        float w0 = __expf(e0 - mn);
        ssum = ssum * sc + w0;
        acc.x = acc.x * sc + w0 * h0.x;
        acc.y = acc.y * sc + w0 * h0.y;
        acc.z = acc.z * sc + w0 * h0.z;
        acc.w = acc.w * sc + w0 * h0.w;
    }

    float inv = 1.0f / (ssum + 1e-9f);
    acc.x *= inv; acc.y *= inv; acc.z *= inv; acc.w *= inv;

    // elu
    acc.x = acc.x > 0.f ? acc.x : expm1f(acc.x);
    acc.y = acc.y > 0.f ? acc.y : expm1f(acc.y);
    acc.z = acc.z > 0.f ? acc.z : expm1f(acc.z);
    acc.w = acc.w > 0.f ? acc.w : expm1f(acc.w);

    if (!FINAL) {
        // write hi/lo bf16 split directly in the next GEMM's fragment-major layout.
        // lane holds dims d = lane*4..lane*4+3; k index = d.
        ushort4 hv, lv;
        hv.x = f2bf(acc.x); lv.x = f2bf(acc.x - bf2f(hv.x));
        hv.y = f2bf(acc.y); lv.y = f2bf(acc.y - bf2f(hv.y));
        hv.z = f2bf(acc.z); lv.z = f2bf(acc.z - bf2f(hv.z));
        hv.w = f2bf(acc.w); lv.w = f2bf(acc.w - bf2f(hv.w));
        int t = v >> 4, mrow = v & 15;
        int kb = lane >> 3;                // 8 k-blocks (K=256)
        int q  = (lane >> 1) & 3;
        int hj = (lane & 1) * 4;
        size_t base = (((size_t)(t * 8 + kb) * 2) * 64 + q * 16 + mrow) * 8 + hj;
        *(ushort4*)&out_f[base] = hv;
        *(ushort4*)&out_f[base + 512] = lv;
    } else {
        // mean over heads (lanes l, l^16, l^32 hold same d-range, different head)
        acc.x += __shfl_xor(acc.x, 16); acc.x += __shfl_xor(acc.x, 32);
        acc.y += __shfl_xor(acc.y, 16); acc.y += __shfl_xor(acc.y, 32);
        acc.z += __shfl_xor(acc.z, 16); acc.z += __shfl_xor(acc.z, 32);
        acc.w += __shfl_xor(acc.w, 16); acc.w += __shfl_xor(acc.w, 32);
        float4 w4 = *(const float4*)&Wout[(lane & 15) * 4];
        float p = 0.25f * (acc.x * w4.x + acc.y * w4.y + acc.z * w4.z + acc.w * w4.w);
        p += __shfl_xor(p, 1);
        p += __shfl_xor(p, 2);
        p += __shfl_xor(p, 4);
        p += __shfl_xor(p, 8);
        if (lane == 0) final_out[v] = fmaxf(p + bout[0], 0.f);
    }
}

extern "C" void kernel_launch(void* const* d_in, const int* in_sizes, int n_in,
                              void* d_out, int out_size, void* d_ws, size_t ws_size,
                              hipStream_t stream) {
    const float* x    = (const float*)d_in[0];
    const int*   src  = (const int*)d_in[1];
    const int*   dst  = (const int*)d_in[2];
    const float* W0   = (const float*)d_in[3];
    const float* al0  = (const float*)d_in[4];
    const float* ar0  = (const float*)d_in[5];
    const float* W1   = (const float*)d_in[6];
    const float* al1  = (const float*)d_in[7];
    const float* ar1  = (const float*)d_in[8];
    const float* W2   = (const float*)d_in[9];
    const float* al2  = (const float*)d_in[10];
    const float* ar2  = (const float*)d_in[11];
    const float* Wout = (const float*)d_in[12];
    const float* bout = (const float*)d_in[13];
    float* outp = (float*)d_out;

    char* ws = (char*)d_ws;
    size_t off = 0;
    auto carve = [&](size_t n) -> char* {
        char* p = ws + off;
        off += (n + 255) & ~(size_t)255;
        return p;
    };
    float*  h_buf  = (float*)carve((size_t)NN * HD * 4);
    ushort* xf     = (ushort*)carve((size_t)NN * HD * 2 * 2);  // fragment-major hi/lo
    float*  el     = (float*)carve((size_t)NN * HEADS * 4);
    float*  er     = (float*)carve((size_t)NN * HEADS * 4);
    int*    cnt    = (int*)carve((size_t)NN * 4);
    int*    cursor = (int*)carve((size_t)NN * 4);
    int*    rowptr = (int*)carve((size_t)(NN + 1) * 4);
    int*    csr_src= (int*)carve((size_t)NE * 4);
    int*    csum   = (int*)carve(64 * 4);
    unsigned short* Wf0 = (unsigned short*)carve((size_t)4 * 16 * 64 * 16 * 2);   // K=128
    unsigned short* Wf1 = (unsigned short*)carve((size_t)8 * 16 * 64 * 16 * 2);   // K=256
    unsigned short* Wf2 = (unsigned short*)carve((size_t)8 * 16 * 64 * 16 * 2);   // K=256

    // ---- prep: all W splits + layer-0 X split in one dispatch ----
    prep_kernel<<<(XSPLIT4 + 255) / 256, 256, 0, stream>>>(x, xf, W0, Wf0, W1, Wf1, W2, Wf2);

    // ---- build dst-CSR: memset, count, chunk_sum, rowptr(+cursor), scatter ----
    hipMemsetAsync(cnt, 0, (size_t)NN * 4, stream);
    count_kernel<<<(NE / 2 + 255) / 256, 256, 0, stream>>>(dst, cnt);
    chunk_sum_kernel<<<NCHUNK, 256, 0, stream>>>(cnt, csum, NN);
    rowptr_kernel<<<NCHUNK, 1024, 0, stream>>>(cnt, csum, rowptr, cursor, NN);
    scatter_kernel<<<(NE / 2 + 255) / 256, 256, 0, stream>>>(src, dst, cursor, csr_src);

    int gGemm = (NN + 63) / 64;            // 782
    int gNode = (NN + 3) / 4;

    // ---- layer 0 ----
    mfma_gemm_kernel<128><<<gGemm, 256, 0, stream>>>(xf, Wf0, h_buf, al0, ar0, el, er);
    gat_node_kernel<0><<<gNode, 256, 0, stream>>>(h_buf, el, er, rowptr, csr_src,
                                                  xf, nullptr, nullptr, nullptr);
    // ---- layer 1 ----
    mfma_gemm_kernel<256><<<gGemm, 256, 0, stream>>>(xf, Wf1, h_buf, al1, ar1, el, er);
    gat_node_kernel<0><<<gNode, 256, 0, stream>>>(h_buf, el, er, rowptr, csr_src,
                                                  xf, nullptr, nullptr, nullptr);
    // ---- layer 2 (final: fused elu + head-mean + Wout + relu) ----
    mfma_gemm_kernel<256><<<gGemm, 256, 0, stream>>>(xf, Wf2, h_buf, al2, ar2, el, er);
    gat_node_kernel<1><<<gNode, 256, 0, stream>>>(h_buf, el, er, rowptr, csr_src,
                                                  nullptr, Wout, bout, outp);
}

// Round 12
// 655.428 us; speedup vs baseline: 1.0718x; 1.0485x over previous
//
#include <hip/hip_runtime.h>
#include <math.h>

#define NN 50000
#define NE 800000
#define HEADS 4
#define HID 64
#define HD 256          // HEADS*HID flattened feature dim
#define NEG_SLOPE 0.2f
#define NCHUNK 49       // ceil(50000/1024)

typedef __attribute__((ext_vector_type(8))) short short8;
typedef __attribute__((ext_vector_type(4))) float f32x4;

__device__ __forceinline__ unsigned short f2bf(float f) {
    unsigned u = __float_as_uint(f);
    u += 0x7fff + ((u >> 16) & 1);          // RNE
    return (unsigned short)(u >> 16);
}
__device__ __forceinline__ float bf2f(unsigned short b) {
    return __uint_as_float(((unsigned)b) << 16);
}

// ---------------- CSR build ----------------
__global__ void count_kernel(const int* __restrict__ dst, int* __restrict__ cnt) {
    int e = (blockIdx.x * 256 + threadIdx.x) * 2;
    if (e + 1 < NE) {
        int2 d = *(const int2*)&dst[e];
        atomicAdd(&cnt[d.x], 1);
        atomicAdd(&cnt[d.y], 1);
    } else if (e < NE) {
        atomicAdd(&cnt[dst[e]], 1);
    }
}

__global__ void chunk_sum_kernel(const int* __restrict__ cnt, int* __restrict__ csum, int n) {
    __shared__ int sdata[256];
    int base = blockIdx.x * 1024;
    int t = threadIdx.x;
    int s = 0;
    for (int i = t; i < 1024; i += 256) {
        int idx = base + i;
        if (idx < n) s += cnt[idx];
    }
    sdata[t] = s; __syncthreads();
    for (int off = 128; off > 0; off >>= 1) {
        if (t < off) sdata[t] += sdata[t + off];
        __syncthreads();
    }
    if (t == 0) csum[blockIdx.x] = sdata[0];
}

// rowptr + cursor-init; chunk offset computed in-block from csum (no separate scan pass)
__global__ void rowptr_kernel(const int* __restrict__ cnt, const int* __restrict__ csum,
                              int* __restrict__ rowptr, int* __restrict__ cursor, int n) {
    __shared__ int buf[1024];
    __shared__ int chunkOff;
    int t = threadIdx.x;
    int idx = blockIdx.x * 1024 + t;
    if (t < 64) {
        int partial = 0;
        for (int i = t; i < blockIdx.x; i += 64) partial += csum[i];
#pragma unroll
        for (int off = 32; off > 0; off >>= 1) partial += __shfl_down(partial, off);
        if (t == 0) chunkOff = partial;
    }
    int v = (idx < n) ? cnt[idx] : 0;
    buf[t] = v; __syncthreads();
    for (int off = 1; off < 1024; off <<= 1) {
        int tmp = (t >= off) ? buf[t - off] : 0;
        __syncthreads();
        buf[t] += tmp;
        __syncthreads();
    }
    int excl = buf[t] - v + chunkOff;
    if (idx < n) { rowptr[idx] = excl; cursor[idx] = excl; }
    if (idx == n - 1) rowptr[n] = excl + v;
}

__global__ void scatter_kernel(const int* __restrict__ src, const int* __restrict__ dst,
                               int* __restrict__ cursor, int* __restrict__ csr_src) {
    int e = (blockIdx.x * 256 + threadIdx.x) * 2;
    if (e + 1 < NE) {
        int2 d = *(const int2*)&dst[e];
        int2 s = *(const int2*)&src[e];
        int p0 = atomicAdd(&cursor[d.x], 1);
        csr_src[p0] = s.x;
        int p1 = atomicAdd(&cursor[d.y], 1);
        csr_src[p1] = s.y;
    } else if (e < NE) {
        int p = atomicAdd(&cursor[dst[e]], 1);
        csr_src[p] = src[e];
    }
}

// ---------------- W fragment-major split (coalesced GEMM B loads) ----------------
// Wf[(((kb*16 + tile)*2 + h)*64 + lane)*8 + j]
//   = split(W[kb*32 + (lane>>4)*8 + j][tile*16 + (lane&15)]),  h=0 hi, h=1 lo.
__device__ __forceinline__ void wsplit_one(const float* W, unsigned short* Wf, int idx) {
    int lane = idx & 63;
    int tile = (idx >> 6) & 15;
    int kb   = idx >> 10;
    int col  = tile * 16 + (lane & 15);
    int krow = kb * 32 + (lane >> 4) * 8;
    unsigned short* p = Wf + ((size_t)(kb * 16 + tile) * 2 * 64 + lane) * 8;
#pragma unroll
    for (int j = 0; j < 8; j++) {
        float v = W[(size_t)(krow + j) * HD + col];
        unsigned short h = f2bf(v);
        unsigned short l = f2bf(v - bf2f(h));
        p[j] = h;
        p[512 + j] = l;            // lo region: +64*8
    }
}

#define XSPLIT4 (NN * 128 / 4)     // 1,600,000 float4s

// prep: layer-0 X -> row-major xh/xl bf16 (coalesced), + all 3 W splits
__global__ void prep_kernel(const float* __restrict__ X, ushort* __restrict__ Xh,
                            ushort* __restrict__ Xl,
                            const float* __restrict__ W0, unsigned short* __restrict__ Wf0,
                            const float* __restrict__ W1, unsigned short* __restrict__ Wf1,
                            const float* __restrict__ W2, unsigned short* __restrict__ Wf2) {
    int idx = blockIdx.x * 256 + threadIdx.x;
    if (idx < XSPLIT4) {
        float4 v = ((const float4*)X)[idx];
        ushort4 h, l;
        h.x = f2bf(v.x); l.x = f2bf(v.x - bf2f(h.x));
        h.y = f2bf(v.y); l.y = f2bf(v.y - bf2f(h.y));
        h.z = f2bf(v.z); l.z = f2bf(v.z - bf2f(h.z));
        h.w = f2bf(v.w); l.w = f2bf(v.w - bf2f(h.w));
        ((ushort4*)Xh)[idx] = h;
        ((ushort4*)Xl)[idx] = l;
    }
    const int n0 = 4 * 16 * 64;            // K=128
    const int n1 = 8 * 16 * 64;            // K=256
    if (idx < n0) wsplit_one(W0, Wf0, idx);
    else if (idx < n0 + n1) wsplit_one(W1, Wf1, idx - n0);
    else if (idx < n0 + 2 * n1) wsplit_one(W2, Wf2, idx - n0 - n1);
}

// ---------------- MFMA GEMM + fused el/er, LDS-staged A ----------------
// H[N,256] = (Xhi+Xlo)[N,K] @ W[K,256], bf16 hi/lo (3 MFMA products, lo*lo dropped).
// Block: 64 rows x 256 cols, 4 waves; wave w owns head w's 64 cols.
// A: row-major global -> registers (coalesced 64B/row) -> fragment-major LDS
//    (b128 conflict-free) -> ds_read_b128 fragments. W: fragment-major global.
template <int K>
__global__ __launch_bounds__(256, 3) void mfma_gemm_kernel(
    const ushort* __restrict__ Xh, const ushort* __restrict__ Xl,
    const unsigned short* __restrict__ Wf,
    float* __restrict__ H,
    const float* __restrict__ al, const float* __restrict__ ar,
    float* __restrict__ el, float* __restrict__ er) {
    constexpr int KB = K / 32;     // k-blocks
    __shared__ ushort ldsA[4 * 2 * 64 * 8];   // [r][h][flane][8] = 8 KB
    int tid = threadIdx.x;
    int w = tid >> 6;              // wave index = head
    int lane = tid & 63;
    int rowBase = blockIdx.x * 64;
    int mrow = lane & 15;          // C: col within tile
    int q = lane >> 4;             // quad

    f32x4 acc[4][4];
#pragma unroll
    for (int r = 0; r < 4; r++)
#pragma unroll
        for (int c = 0; c < 4; c++) {
            f32x4 z = {0.f, 0.f, 0.f, 0.f};
            acc[r][c] = z;
        }

    // staging thread mapping: row = tid>>2 (0..63), qq = tid&3
    int srow = tid >> 2, qq = tid & 3;
    int grow = rowBase + srow;
    grow = grow < NN ? grow : NN - 1;      // clamp; OOB rows never stored
    const ushort* xhp = Xh + (size_t)grow * K + qq * 8;
    const ushort* xlp = Xl + (size_t)grow * K + qq * 8;
    int sr = srow >> 4, smrow = srow & 15;
    int flane = qq * 16 + smrow;
    ushort* ldsWhi = &ldsA[((size_t)(sr * 2 + 0) * 64 + flane) * 8];
    ushort* ldsWlo = &ldsA[((size_t)(sr * 2 + 1) * 64 + flane) * 8];

    short8 sAh = *(const short8*)xhp;
    short8 sAl = *(const short8*)xlp;

    for (int kb = 0; kb < KB; kb++) {
        __syncthreads();                   // previous iter's LDS reads done
        *(short8*)ldsWhi = sAh;
        *(short8*)ldsWlo = sAl;
        __syncthreads();
        if (kb + 1 < KB) {                 // prefetch next A tile (overlaps compute)
            sAh = *(const short8*)(xhp + (kb + 1) * 32);
            sAl = *(const short8*)(xlp + (kb + 1) * 32);
        }
        short8 Wh[4], Wl_[4];
#pragma unroll
        for (int c = 0; c < 4; c++) {
            const unsigned short* wp =
                Wf + (((size_t)(kb * 16 + w * 4 + c) * 2) * 64 + lane) * 8;
            Wh[c]  = *(const short8*)wp;
            Wl_[c] = *(const short8*)(wp + 512);
        }
        short8 Ah[4], Al_[4];
#pragma unroll
        for (int r = 0; r < 4; r++) {
            Ah[r]  = *(const short8*)&ldsA[((size_t)(r * 2 + 0) * 64 + lane) * 8];
            Al_[r] = *(const short8*)&ldsA[((size_t)(r * 2 + 1) * 64 + lane) * 8];
        }
#pragma unroll
        for (int c = 0; c < 4; c++)
#pragma unroll
            for (int r = 0; r < 4; r++) {
                acc[r][c] = __builtin_amdgcn_mfma_f32_16x16x32_bf16(Ah[r],  Wh[c],  acc[r][c], 0, 0, 0);
                acc[r][c] = __builtin_amdgcn_mfma_f32_16x16x32_bf16(Ah[r],  Wl_[c], acc[r][c], 0, 0, 0);
                acc[r][c] = __builtin_amdgcn_mfma_f32_16x16x32_bf16(Al_[r], Wh[c],  acc[r][c], 0, 0, 0);
            }
    }

    // --- epilogue: store H + fused el/er (head w) ---
    int n0 = w * 64;
    float alv[4], arv[4];
#pragma unroll
    for (int c = 0; c < 4; c++) {
        alv[c] = al[n0 + c * 16 + mrow];
        arv[c] = ar[n0 + c * 16 + mrow];
    }
#pragma unroll
    for (int r = 0; r < 4; r++) {
        float pl[4] = {0.f, 0.f, 0.f, 0.f};
        float pr[4] = {0.f, 0.f, 0.f, 0.f};
#pragma unroll
        for (int c = 0; c < 4; c++)
#pragma unroll
            for (int g = 0; g < 4; g++) {
                pl[g] += acc[r][c][g] * alv[c];
                pr[g] += acc[r][c][g] * arv[c];
            }
#pragma unroll
        for (int g = 0; g < 4; g++) {
#pragma unroll
            for (int off = 1; off < 16; off <<= 1) {
                pl[g] += __shfl_xor(pl[g], off);
                pr[g] += __shfl_xor(pr[g], off);
            }
        }
#pragma unroll
        for (int g = 0; g < 4; g++) {
            int row = rowBase + r * 16 + q * 4 + g;
            if (row < NN) {
#pragma unroll
                for (int c = 0; c < 4; c++)
                    H[(size_t)row * HD + n0 + c * 16 + mrow] = acc[r][c][g];
                if (mrow == 0) {
                    el[row * 4 + w] = pl[g];
                    er[row * 4 + w] = pr[g];
                }
            }
        }
    }
}

// ---------------- GAT per-node: single-pass flash softmax, unroll-2 ----------------
__device__ __forceinline__ float lrelu(float x) { return x > 0.f ? x : NEG_SLOPE * x; }

template <int FINAL>
__global__ __launch_bounds__(256) void gat_node_kernel(
    const float* __restrict__ H, const float* __restrict__ el, const float* __restrict__ er,
    const int* __restrict__ rowptr, const int* __restrict__ csr_src,
    ushort* __restrict__ out_hi, ushort* __restrict__ out_lo,
    const float* __restrict__ Wout, const float* __restrict__ bout,
    float* __restrict__ final_out) {
    int wave = threadIdx.x >> 6, lane = threadIdx.x & 63;
    int v = blockIdx.x * 4 + wave;
    if (v >= NN) return;
    int beg = rowptr[v], end = rowptr[v + 1];

    int hh = lane >> 4;                    // head for this lane's feature slice
    float er_h = er[v * 4 + hh];

    float m = -INFINITY;
    float ssum = 0.f;
    float4 acc = make_float4(0.f, 0.f, 0.f, 0.f);

    int idx = beg;
    for (; idx + 2 <= end; idx += 2) {
        int s0 = csr_src[idx];
        int s1 = csr_src[idx + 1];
        float el0 = el[s0 * 4 + hh];
        float el1 = el[s1 * 4 + hh];
        float4 h0 = *(const float4*)&H[(long)s0 * HD + lane * 4];
        float4 h1 = *(const float4*)&H[(long)s1 * HD + lane * 4];
        float e0 = lrelu(el0 + er_h);
        float e1 = lrelu(el1 + er_h);
        float mn = fmaxf(m, fmaxf(e0, e1));
        float sc = __expf(m - mn);
        float w0 = __expf(e0 - mn);
        float w1 = __expf(e1 - mn);
        ssum = ssum * sc + w0 + w1;
        acc.x = acc.x * sc + w0 * h0.x + w1 * h1.x;
        acc.y = acc.y * sc + w0 * h0.y + w1 * h1.y;
        acc.z = acc.z * sc + w0 * h0.z + w1 * h1.z;
        acc.w = acc.w * sc + w0 * h0.w + w1 * h1.w;
        m = mn;
    }
    if (idx < end) {
        int s0 = csr_src[idx];
        float el0 = el[s0 * 4 + hh];
        float4 h0 = *(const float4*)&H[(long)s0 * HD + lane * 4];
        float e0 = lrelu(el0 + er_h);
        float mn = fmaxf(m, e0);
        float sc = __expf(m - mn);
        float w0 = __expf(e0 - mn);
        ssum = ssum * sc + w0;
        acc.x = acc.x * sc + w0 * h0.x;
        acc.y = acc.y * sc + w0 * h0.y;
        acc.z = acc.z * sc + w0 * h0.z;
        acc.w = acc.w * sc + w0 * h0.w;
    }

    float inv = 1.0f / (ssum + 1e-9f);
    acc.x *= inv; acc.y *= inv; acc.z *= inv; acc.w *= inv;

    // elu
    acc.x = acc.x > 0.f ? acc.x : expm1f(acc.x);
    acc.y = acc.y > 0.f ? acc.y : expm1f(acc.y);
    acc.z = acc.z > 0.f ? acc.z : expm1f(acc.z);
    acc.w = acc.w > 0.f ? acc.w : expm1f(acc.w);

    if (!FINAL) {
        // row-major hi/lo bf16 (contiguous 512B/row/buffer writes) — next GEMM's A
        ushort4 hv, lv;
        hv.x = f2bf(acc.x); lv.x = f2bf(acc.x - bf2f(hv.x));
        hv.y = f2bf(acc.y); lv.y = f2bf(acc.y - bf2f(hv.y));
        hv.z = f2bf(acc.z); lv.z = f2bf(acc.z - bf2f(hv.z));
        hv.w = f2bf(acc.w); lv.w = f2bf(acc.w - bf2f(hv.w));
        *(ushort4*)&out_hi[(size_t)v * HD + lane * 4] = hv;
        *(ushort4*)&out_lo[(size_t)v * HD + lane * 4] = lv;
    } else {
        // mean over heads (lanes l, l^16, l^32 hold same d-range, different head)
        acc.x += __shfl_xor(acc.x, 16); acc.x += __shfl_xor(acc.x, 32);
        acc.y += __shfl_xor(acc.y, 16); acc.y += __shfl_xor(acc.y, 32);
        acc.z += __shfl_xor(acc.z, 16); acc.z += __shfl_xor(acc.z, 32);
        acc.w += __shfl_xor(acc.w, 16); acc.w += __shfl_xor(acc.w, 32);
        float4 w4 = *(const float4*)&Wout[(lane & 15) * 4];
        float p = 0.25f * (acc.x * w4.x + acc.y * w4.y + acc.z * w4.z + acc.w * w4.w);
        p += __shfl_xor(p, 1);
        p += __shfl_xor(p, 2);
        p += __shfl_xor(p, 4);
        p += __shfl_xor(p, 8);
        if (lane == 0) final_out[v] = fmaxf(p + bout[0], 0.f);
    }
}

extern "C" void kernel_launch(void* const* d_in, const int* in_sizes, int n_in,
                              void* d_out, int out_size, void* d_ws, size_t ws_size,
                              hipStream_t stream) {
    const float* x    = (const float*)d_in[0];
    const int*   src  = (const int*)d_in[1];
    const int*   dst  = (const int*)d_in[2];
    const float* W0   = (const float*)d_in[3];
    const float* al0  = (const float*)d_in[4];
    const float* ar0  = (const float*)d_in[5];
    const float* W1   = (const float*)d_in[6];
    const float* al1  = (const float*)d_in[7];
    const float* ar1  = (const float*)d_in[8];
    const float* W2   = (const float*)d_in[9];
    const float* al2  = (const float*)d_in[10];
    const float* ar2  = (const float*)d_in[11];
    const float* Wout = (const float*)d_in[12];
    const float* bout = (const float*)d_in[13];
    float* outp = (float*)d_out;

    char* ws = (char*)d_ws;
    size_t off = 0;
    auto carve = [&](size_t n) -> char* {
        char* p = ws + off;
        off += (n + 255) & ~(size_t)255;
        return p;
    };
    float*  h_buf  = (float*)carve((size_t)NN * HD * 4);
    ushort* xh     = (ushort*)carve((size_t)NN * HD * 2);   // A hi, row-major
    ushort* xl     = (ushort*)carve((size_t)NN * HD * 2);   // A lo, row-major
    float*  el     = (float*)carve((size_t)NN * HEADS * 4);
    float*  er     = (float*)carve((size_t)NN * HEADS * 4);
    int*    cnt    = (int*)carve((size_t)NN * 4);
    int*    cursor = (int*)carve((size_t)NN * 4);
    int*    rowptr = (int*)carve((size_t)(NN + 1) * 4);
    int*    csr_src= (int*)carve((size_t)NE * 4);
    int*    csum   = (int*)carve(64 * 4);
    unsigned short* Wf0 = (unsigned short*)carve((size_t)4 * 16 * 64 * 16 * 2);   // K=128
    unsigned short* Wf1 = (unsigned short*)carve((size_t)8 * 16 * 64 * 16 * 2);   // K=256
    unsigned short* Wf2 = (unsigned short*)carve((size_t)8 * 16 * 64 * 16 * 2);   // K=256

    // ---- prep: all W splits + layer-0 X split in one dispatch ----
    prep_kernel<<<(XSPLIT4 + 255) / 256, 256, 0, stream>>>(x, xh, xl, W0, Wf0, W1, Wf1, W2, Wf2);

    // ---- build dst-CSR: memset, count, chunk_sum, rowptr(+cursor), scatter ----
    hipMemsetAsync(cnt, 0, (size_t)NN * 4, stream);
    count_kernel<<<(NE / 2 + 255) / 256, 256, 0, stream>>>(dst, cnt);
    chunk_sum_kernel<<<NCHUNK, 256, 0, stream>>>(cnt, csum, NN);
    rowptr_kernel<<<NCHUNK, 1024, 0, stream>>>(cnt, csum, rowptr, cursor, NN);
    scatter_kernel<<<(NE / 2 + 255) / 256, 256, 0, stream>>>(src, dst, cursor, csr_src);

    int gGemm = (NN + 63) / 64;            // 782
    int gNode = (NN + 3) / 4;

    // ---- layer 0 ----
    mfma_gemm_kernel<128><<<gGemm, 256, 0, stream>>>(xh, xl, Wf0, h_buf, al0, ar0, el, er);
    gat_node_kernel<0><<<gNode, 256, 0, stream>>>(h_buf, el, er, rowptr, csr_src,
                                                  xh, xl, nullptr, nullptr, nullptr);
    // ---- layer 1 ----
    mfma_gemm_kernel<256><<<gGemm, 256, 0, stream>>>(xh, xl, Wf1, h_buf, al1, ar1, el, er);
    gat_node_kernel<0><<<gNode, 256, 0, stream>>>(h_buf, el, er, rowptr, csr_src,
                                                  xh, xl, nullptr, nullptr, nullptr);
    // ---- layer 2 (final: fused elu + head-mean + Wout + relu) ----
    mfma_gemm_kernel<256><<<gGemm, 256, 0, stream>>>(xh, xl, Wf2, h_buf, al2, ar2, el, er);
    gat_node_kernel<1><<<gNode, 256, 0, stream>>>(h_buf, el, er, rowptr, csr_src,
                                                  nullptr, nullptr, Wout, bout, outp);
}